// Round 1
// 1247.712 us; speedup vs baseline: 1.3882x; 1.3882x over previous
//
#include <hip/hip_runtime.h>

#define D_MODEL 1024
#define N_HEADS 16
#define D_K     64
#define BB      2
#define SS      2048
#define M_TOT   (BB * SS)          // 4096

typedef __attribute__((ext_vector_type(8))) short short8;
typedef __attribute__((ext_vector_type(4))) float f32x4;

// ---------------------------------------------------------------------------
// fp32 -> (hi, lo) bf16 split.  x ~= hi + lo with residual ~2^-17 |x|.
// ---------------------------------------------------------------------------
__device__ __forceinline__ unsigned short bf_rne(float x) {
    unsigned u = __builtin_bit_cast(unsigned, x);
    u += 0x7fff + ((u >> 16) & 1);
    return (unsigned short)(u >> 16);
}
__device__ __forceinline__ void split2(float x, unsigned short& h, unsigned short& l) {
    unsigned short hh = bf_rne(x);
    float hf = __builtin_bit_cast(float, ((unsigned)hh) << 16);
    l = bf_rne(x - hf);
    h = hh;
}

// LDS swizzle: bf16 tile row r (64 elems); XOR 16B-chunk index with (r&7).
// Fragment reads (16 lanes, consecutive rows, same k) land 2-way max = free.
__device__ __forceinline__ int swz(int r, int k) {
    return r * 64 + ((((k >> 3) ^ (r & 7)) << 3) | (k & 7));
}

// ---------------------------------------------------------------------------
// Elementwise fp32 -> split-bf16 planes (weights).
// ---------------------------------------------------------------------------
__global__ __launch_bounds__(256) void split_f32(
    const float* __restrict__ in, unsigned short* __restrict__ h,
    unsigned short* __restrict__ l, int n4)
{
    int i = blockIdx.x * 256 + threadIdx.x;
    if (i >= n4) return;
    float4 v = ((const float4*)in)[i];
    unsigned short hh[4], ll[4];
    split2(v.x, hh[0], ll[0]); split2(v.y, hh[1], ll[1]);
    split2(v.z, hh[2], ll[2]); split2(v.w, hh[3], ll[3]);
    *(ushort4*)&h[i * 4] = make_ushort4(hh[0], hh[1], hh[2], hh[3]);
    *(ushort4*)&l[i * 4] = make_ushort4(ll[0], ll[1], ll[2], ll[3]);
}

// ---------------------------------------------------------------------------
// bf16x4-split MFMA GEMM:  C = scale * (A @ B^T) [+ bias]
//   A: fp32 [M,K] (lda, z-stride sAz), converted to hi/lo during staging.
//   B: pre-split bf16 planes [N,K] (ldb, z-stride sBz).
// Tile: BM=128 x BN(128|64), BK=64, 256 thr = 4 waves (2x2), wave 64 x BN/2.
// MFMA v_mfma_f32_16x16x32_bf16; 4 split terms (hh, lh, hl, ll).
// STORE: 0 fp32 [z][m*ldc+n]          (scores / out)
//        1 fp32 head-split  [b,h,s,d] (qh)
//        2 split head-split [b,h,s,d] (kh planes)
//        3 split head-T     [b,h,d,s] (vht planes)
//        4 fp32 head-merged [b,s,h*64+n] from z=(b,h) (PV -> oh)
// ---------------------------------------------------------------------------
template <int BN, int STORE, bool BIAS>
__global__ __launch_bounds__(256, 2) void gemm3(
    const float* __restrict__ A, long sAz, int lda,
    const unsigned short* __restrict__ Bh, const unsigned short* __restrict__ Bl,
    long sBz, int ldb,
    const float* __restrict__ bias,
    float* __restrict__ Cf, unsigned short* __restrict__ Ch,
    unsigned short* __restrict__ Cl,
    long sCz, int ldc, int K, float scale)
{
    constexpr int NF = (BN == 128) ? 4 : 2;   // n-fragments per wave
    constexpr int PB = BN / 32;               // B staging row-groups

    const int z = blockIdx.z;
    A  += (long)z * sAz;
    Bh += (long)z * sBz;
    Bl += (long)z * sBz;

    const int m0 = blockIdx.y * 128;
    const int n0 = blockIdx.x * BN;
    const int t  = threadIdx.x;
    const int lane = t & 63;
    const int wy = t >> 7;          // wave row (0..1)
    const int wx = (t >> 6) & 1;    // wave col (0..1)

    __shared__ __align__(16) unsigned short Ahs[128 * 64];
    __shared__ __align__(16) unsigned short Als[128 * 64];
    __shared__ __align__(16) unsigned short Bhs[BN * 64];
    __shared__ __align__(16) unsigned short Bls[BN * 64];

    const int sr = t >> 3;          // staging row 0..31
    const int sc = (t & 7) * 8;     // staging k-offset

    f32x4 acc[4][NF];
#pragma unroll
    for (int i = 0; i < 4; ++i)
#pragma unroll
        for (int j = 0; j < NF; ++j) acc[i][j] = (f32x4){0.f, 0.f, 0.f, 0.f};

    for (int k0 = 0; k0 < K; k0 += 64) {
        // ---- global loads (before barrier: overlap with prev MFMA) ----
        float4 a0[4], a1[4];
#pragma unroll
        for (int p = 0; p < 4; ++p) {
            const float* s = &A[(long)(m0 + sr + 32 * p) * lda + k0 + sc];
            a0[p] = *(const float4*)s;
            a1[p] = *(const float4*)(s + 4);
        }
        short8 gbh[PB], gbl[PB];
#pragma unroll
        for (int p = 0; p < PB; ++p) {
            const long bo = (long)(n0 + sr + 32 * p) * ldb + k0 + sc;
            gbh[p] = *(const short8*)&Bh[bo];
            gbl[p] = *(const short8*)&Bl[bo];
        }
        __syncthreads();
        // ---- convert + LDS write ----
#pragma unroll
        for (int p = 0; p < 4; ++p) {
            union { short8 v; unsigned short u[8]; } ph, pl;
            float f[8] = {a0[p].x, a0[p].y, a0[p].z, a0[p].w,
                          a1[p].x, a1[p].y, a1[p].z, a1[p].w};
#pragma unroll
            for (int e = 0; e < 8; ++e) split2(f[e], ph.u[e], pl.u[e]);
            const int idx = swz(sr + 32 * p, sc);
            *(short8*)&Ahs[idx] = ph.v;
            *(short8*)&Als[idx] = pl.v;
        }
#pragma unroll
        for (int p = 0; p < PB; ++p) {
            const int idx = swz(sr + 32 * p, sc);
            *(short8*)&Bhs[idx] = gbh[p];
            *(short8*)&Bls[idx] = gbl[p];
        }
        __syncthreads();

        // ---- MFMA: 2 k-subtiles of 32 ----
#pragma unroll
        for (int ks = 0; ks < 2; ++ks) {
            const int fr = lane & 15;
            const int fk = ks * 32 + (lane >> 4) * 8;
            short8 ah[4], al[4], bh8[NF], bl8[NF];
#pragma unroll
            for (int i = 0; i < 4; ++i) {
                const int idx = swz(wy * 64 + i * 16 + fr, fk);
                ah[i] = *(const short8*)&Ahs[idx];
                al[i] = *(const short8*)&Als[idx];
            }
#pragma unroll
            for (int j = 0; j < NF; ++j) {
                const int idx = swz(wx * (16 * NF) + j * 16 + fr, fk);
                bh8[j] = *(const short8*)&Bhs[idx];
                bl8[j] = *(const short8*)&Bls[idx];
            }
#pragma unroll
            for (int i = 0; i < 4; ++i)
#pragma unroll
                for (int j = 0; j < NF; ++j) {
                    acc[i][j] = __builtin_amdgcn_mfma_f32_16x16x32_bf16(ah[i], bh8[j], acc[i][j], 0, 0, 0);
                    acc[i][j] = __builtin_amdgcn_mfma_f32_16x16x32_bf16(al[i], bh8[j], acc[i][j], 0, 0, 0);
                    acc[i][j] = __builtin_amdgcn_mfma_f32_16x16x32_bf16(ah[i], bl8[j], acc[i][j], 0, 0, 0);
                    acc[i][j] = __builtin_amdgcn_mfma_f32_16x16x32_bf16(al[i], bl8[j], acc[i][j], 0, 0, 0);
                }
        }
    }

    // ---- epilogue ----
    const int fr = lane & 15;
    const int fq = lane >> 4;
#pragma unroll
    for (int j = 0; j < NF; ++j) {
        const int n = n0 + wx * (16 * NF) + j * 16 + fr;
        const float bj = BIAS ? bias[n] : 0.0f;
#pragma unroll
        for (int i = 0; i < 4; ++i)
#pragma unroll
            for (int r = 0; r < 4; ++r) {
                const int m = m0 + wy * 64 + i * 16 + fq * 4 + r;
                const float val = acc[i][j][r] * scale + bj;
                if (STORE == 0) {
                    Cf[(long)z * sCz + (long)m * ldc + n] = val;
                } else if (STORE == 1) {
                    const int b = m >> 11, s = m & 2047, h = n >> 6, d = n & 63;
                    Cf[(((long)(b * N_HEADS + h)) * SS + s) * 64 + d] = val;
                } else if (STORE == 2) {
                    const int b = m >> 11, s = m & 2047, h = n >> 6, d = n & 63;
                    unsigned short hh, ll; split2(val, hh, ll);
                    const long idx = (((long)(b * N_HEADS + h)) * SS + s) * 64 + d;
                    Ch[idx] = hh; Cl[idx] = ll;
                } else if (STORE == 3) {
                    const int b = m >> 11, s = m & 2047, h = n >> 6, d = n & 63;
                    unsigned short hh, ll; split2(val, hh, ll);
                    const long idx = (((long)(b * N_HEADS + h)) * 64 + d) * SS + s;
                    Ch[idx] = hh; Cl[idx] = ll;
                } else {  // STORE 4
                    const int b = z >> 4, h = z & 15;
                    Cf[((long)(b * SS + m)) * D_MODEL + h * 64 + n] = val;
                }
            }
    }
}

// ---------------------------------------------------------------------------
// Row softmax in-place: one block per row of 2048, 256 threads x 8 elems.
// ---------------------------------------------------------------------------
__global__ __launch_bounds__(256) void softmax_rows(float* __restrict__ attn)
{
    const long row = blockIdx.x;
    float* p = attn + row * (long)SS;
    const int t = threadIdx.x;

    float4 v0 = *(const float4*)&p[t * 4];
    float4 v1 = *(const float4*)&p[(t + 256) * 4];

    float m = fmaxf(fmaxf(fmaxf(v0.x, v0.y), fmaxf(v0.z, v0.w)),
                    fmaxf(fmaxf(v1.x, v1.y), fmaxf(v1.z, v1.w)));
#pragma unroll
    for (int off = 32; off >= 1; off >>= 1)
        m = fmaxf(m, __shfl_xor(m, off));

    __shared__ float red[8];
    if ((t & 63) == 0) red[t >> 6] = m;
    __syncthreads();
    m = fmaxf(fmaxf(red[0], red[1]), fmaxf(red[2], red[3]));

    v0.x = __expf(v0.x - m); v0.y = __expf(v0.y - m);
    v0.z = __expf(v0.z - m); v0.w = __expf(v0.w - m);
    v1.x = __expf(v1.x - m); v1.y = __expf(v1.y - m);
    v1.z = __expf(v1.z - m); v1.w = __expf(v1.w - m);

    float s = (v0.x + v0.y + v0.z + v0.w) + (v1.x + v1.y + v1.z + v1.w);
#pragma unroll
    for (int off = 32; off >= 1; off >>= 1)
        s += __shfl_xor(s, off);
    if ((t & 63) == 0) red[4 + (t >> 6)] = s;
    __syncthreads();
    s = (red[4] + red[5]) + (red[6] + red[7]);

    const float r = 1.0f / s;
    v0.x *= r; v0.y *= r; v0.z *= r; v0.w *= r;
    v1.x *= r; v1.y *= r; v1.z *= r; v1.w *= r;

    *(float4*)&p[t * 4] = v0;
    *(float4*)&p[(t + 256) * 4] = v1;
}

// ---------------------------------------------------------------------------
extern "C" void kernel_launch(void* const* d_in, const int* in_sizes, int n_in,
                              void* d_out, int out_size, void* d_ws, size_t ws_size,
                              hipStream_t stream)
{
    const float* q  = (const float*)d_in[0];
    const float* k  = (const float*)d_in[1];
    const float* v  = (const float*)d_in[2];
    const float* wq = (const float*)d_in[3];
    const float* bq = (const float*)d_in[4];
    const float* wk = (const float*)d_in[5];
    const float* bk = (const float*)d_in[6];
    const float* wv = (const float*)d_in[7];
    const float* bv = (const float*)d_in[8];
    const float* wo = (const float*)d_in[9];
    const float* bo = (const float*)d_in[10];

    float* out  = (float*)d_out;                         // [2,2048,1024]
    float* attn = out + (long)BB * SS * D_MODEL;         // [2,16,2048,2048]

    // --- workspace layout (64 MB total, same footprint as previous kernel) ---
    // [ 0,16)MB qh fp32           (dead after scores -> reused for wo planes)
    // [16,24)MB kh_hi  [24,32)MB kh_lo
    // [32,40)MB vt_hi  [40,48)MB vt_lo          (vh transposed [b,h,d,s])
    // [48,64)MB oh fp32           (holds wq/wk/wv planes until PV writes it)
    char* ws = (char*)d_ws;
    float*          qh    = (float*)ws;
    unsigned short* kh_hi = (unsigned short*)(ws + (16L << 20));
    unsigned short* kh_lo = (unsigned short*)(ws + (24L << 20));
    unsigned short* vt_hi = (unsigned short*)(ws + (32L << 20));
    unsigned short* vt_lo = (unsigned short*)(ws + (40L << 20));
    float*          oh    = (float*)(ws + (48L << 20));
    unsigned short* wq_hi = (unsigned short*)(ws + (48L << 20));
    unsigned short* wq_lo = (unsigned short*)(ws + (50L << 20));
    unsigned short* wk_hi = (unsigned short*)(ws + (52L << 20));
    unsigned short* wk_lo = (unsigned short*)(ws + (54L << 20));
    unsigned short* wv_hi = (unsigned short*)(ws + (56L << 20));
    unsigned short* wv_lo = (unsigned short*)(ws + (58L << 20));
    unsigned short* wo_hi = (unsigned short*)(ws);               // alias qh
    unsigned short* wo_lo = (unsigned short*)(ws + (2L << 20));  // alias qh

    const dim3 blk(256);
    const int NW4 = (D_MODEL * D_MODEL) / 4;   // 262144

    // Split weights for the projections (wq/wk/wv live in the oh region).
    hipLaunchKernelGGL(split_f32, dim3(1024), blk, 0, stream, wq, wq_hi, wq_lo, NW4);
    hipLaunchKernelGGL(split_f32, dim3(1024), blk, 0, stream, wk, wk_hi, wk_lo, NW4);
    hipLaunchKernelGGL(split_f32, dim3(1024), blk, 0, stream, wv, wv_hi, wv_lo, NW4);

    // Projections: M=4096, N=1024, K=1024
    const dim3 gproj(D_MODEL / 128, M_TOT / 128, 1);
    hipLaunchKernelGGL((gemm3<128, 1, true>), gproj, blk, 0, stream,
                       q, 0L, D_MODEL, wq_hi, wq_lo, 0L, D_MODEL, bq,
                       qh, (unsigned short*)nullptr, (unsigned short*)nullptr,
                       0L, 0, D_MODEL, 1.0f);
    hipLaunchKernelGGL((gemm3<128, 2, true>), gproj, blk, 0, stream,
                       k, 0L, D_MODEL, wk_hi, wk_lo, 0L, D_MODEL, bk,
                       (float*)nullptr, kh_hi, kh_lo, 0L, 0, D_MODEL, 1.0f);
    hipLaunchKernelGGL((gemm3<128, 3, true>), gproj, blk, 0, stream,
                       v, 0L, D_MODEL, wv_hi, wv_lo, 0L, D_MODEL, bv,
                       (float*)nullptr, vt_hi, vt_lo, 0L, 0, D_MODEL, 1.0f);

    // Scores: per (b,h)  [2048x64] @ [2048x64]^T / 8 -> attn raw
    const dim3 gsc(SS / 128, SS / 128, BB * N_HEADS);
    hipLaunchKernelGGL((gemm3<128, 0, false>), gsc, blk, 0, stream,
                       qh, (long)SS * 64, 64, kh_hi, kh_lo, (long)SS * 64, 64,
                       (const float*)nullptr,
                       attn, (unsigned short*)nullptr, (unsigned short*)nullptr,
                       (long)SS * SS, SS, D_K, 0.125f);

    // Split wo into the (now dead) qh region.
    hipLaunchKernelGGL(split_f32, dim3(1024), blk, 0, stream, wo, wo_hi, wo_lo, NW4);

    // Softmax rows in-place
    hipLaunchKernelGGL(softmax_rows, dim3(BB * N_HEADS * SS), blk, 0, stream, attn);

    // PV: attn[2048,2048] @ vt^T[2048,64]  (vt is [d][s], so NT form) -> oh
    const dim3 gpv(1, SS / 128, BB * N_HEADS);
    hipLaunchKernelGGL((gemm3<64, 4, false>), gpv, blk, 0, stream,
                       attn, (long)SS * SS, SS, vt_hi, vt_lo, (long)64 * SS, SS,
                       (const float*)nullptr,
                       oh, (unsigned short*)nullptr, (unsigned short*)nullptr,
                       0L, 0, SS, 1.0f);

    // Output projection: oh @ wo^T + bo -> out
    hipLaunchKernelGGL((gemm3<128, 0, true>), gproj, blk, 0, stream,
                       oh, 0L, D_MODEL, wo_hi, wo_lo, 0L, D_MODEL, bo,
                       out, (unsigned short*)nullptr, (unsigned short*)nullptr,
                       0L, D_MODEL, D_MODEL, 1.0f);
}

// Round 2
// 1147.659 us; speedup vs baseline: 1.5092x; 1.0872x over previous
//
#include <hip/hip_runtime.h>

#define D_MODEL 1024
#define N_HEADS 16
#define D_K     64
#define BB      2
#define SS      2048
#define M_TOT   (BB * SS)          // 4096

typedef __attribute__((ext_vector_type(8))) short short8;
typedef __attribute__((ext_vector_type(4))) float f32x4;

// ---------------------------------------------------------------------------
// fp32 -> (hi, lo) bf16 split.  x ~= hi + lo with residual ~2^-17 |x|.
// ---------------------------------------------------------------------------
__device__ __forceinline__ unsigned short bf_rne(float x) {
    unsigned u = __builtin_bit_cast(unsigned, x);
    u += 0x7fff + ((u >> 16) & 1);
    return (unsigned short)(u >> 16);
}
__device__ __forceinline__ void split2(float x, unsigned short& h, unsigned short& l) {
    unsigned short hh = bf_rne(x);
    float hf = __builtin_bit_cast(float, ((unsigned)hh) << 16);
    l = bf_rne(x - hf);
    h = hh;
}

// LDS swizzle: bf16 tile row r (64 elems); XOR 16B-chunk index with (r&7).
__device__ __forceinline__ int swz(int r, int k) {
    return r * 64 + ((((k >> 3) ^ (r & 7)) << 3) | (k & 7));
}

// ---------------------------------------------------------------------------
// Elementwise fp32 -> split-bf16 planes (weights).
// ---------------------------------------------------------------------------
__global__ __launch_bounds__(256) void split_f32(
    const float* __restrict__ in, unsigned short* __restrict__ h,
    unsigned short* __restrict__ l, int n4)
{
    int i = blockIdx.x * 256 + threadIdx.x;
    if (i >= n4) return;
    float4 v = ((const float4*)in)[i];
    unsigned short hh[4], ll[4];
    split2(v.x, hh[0], ll[0]); split2(v.y, hh[1], ll[1]);
    split2(v.z, hh[2], ll[2]); split2(v.w, hh[3], ll[3]);
    *(ushort4*)&h[i * 4] = make_ushort4(hh[0], hh[1], hh[2], hh[3]);
    *(ushort4*)&l[i * 4] = make_ushort4(ll[0], ll[1], ll[2], ll[3]);
}

// ---------------------------------------------------------------------------
// bf16x3-split MFMA GEMM:  C = scale * (A @ B^T) [+ bias]
//   A: fp32 [M,K], converted to hi/lo during staging. B: pre-split planes.
// STORE: 0 fp32 [m*ldc+n]               (out-projection)
//        2 split head-split [b,h,s,d]   (qh / kh planes)
//        3 split head-T     [b,h,d,s]   (vht planes)
// ---------------------------------------------------------------------------
template <int STORE, bool BIAS>
__global__ __launch_bounds__(256, 2) void gemm3(
    const float* __restrict__ A, int lda,
    const unsigned short* __restrict__ Bh, const unsigned short* __restrict__ Bl,
    int ldb,
    const float* __restrict__ bias,
    float* __restrict__ Cf, unsigned short* __restrict__ Ch,
    unsigned short* __restrict__ Cl,
    int ldc, int K)
{
    const int m0 = blockIdx.y * 128;
    const int n0 = blockIdx.x * 128;
    const int t  = threadIdx.x;
    const int lane = t & 63;
    const int wy = t >> 7;
    const int wx = (t >> 6) & 1;

    __shared__ __align__(16) unsigned short Ahs[128 * 64];
    __shared__ __align__(16) unsigned short Als[128 * 64];
    __shared__ __align__(16) unsigned short Bhs[128 * 64];
    __shared__ __align__(16) unsigned short Bls[128 * 64];

    const int sr = t >> 3;
    const int sc = (t & 7) * 8;

    f32x4 acc[4][4];
#pragma unroll
    for (int i = 0; i < 4; ++i)
#pragma unroll
        for (int j = 0; j < 4; ++j) acc[i][j] = (f32x4){0.f, 0.f, 0.f, 0.f};

    for (int k0 = 0; k0 < K; k0 += 64) {
        float4 a0[4], a1[4];
#pragma unroll
        for (int p = 0; p < 4; ++p) {
            const float* s = &A[(long)(m0 + sr + 32 * p) * lda + k0 + sc];
            a0[p] = *(const float4*)s;
            a1[p] = *(const float4*)(s + 4);
        }
        short8 gbh[4], gbl[4];
#pragma unroll
        for (int p = 0; p < 4; ++p) {
            const long bo = (long)(n0 + sr + 32 * p) * ldb + k0 + sc;
            gbh[p] = *(const short8*)&Bh[bo];
            gbl[p] = *(const short8*)&Bl[bo];
        }
        __syncthreads();
#pragma unroll
        for (int p = 0; p < 4; ++p) {
            union { short8 v; unsigned short u[8]; } ph, pl;
            float f[8] = {a0[p].x, a0[p].y, a0[p].z, a0[p].w,
                          a1[p].x, a1[p].y, a1[p].z, a1[p].w};
#pragma unroll
            for (int e = 0; e < 8; ++e) split2(f[e], ph.u[e], pl.u[e]);
            const int idx = swz(sr + 32 * p, sc);
            *(short8*)&Ahs[idx] = ph.v;
            *(short8*)&Als[idx] = pl.v;
            *(short8*)&Bhs[idx] = gbh[p];
            *(short8*)&Bls[idx] = gbl[p];
        }
        __syncthreads();

#pragma unroll
        for (int ks = 0; ks < 2; ++ks) {
            const int fr = lane & 15;
            const int fk = ks * 32 + (lane >> 4) * 8;
            short8 ah[4], al[4], bh8[4], bl8[4];
#pragma unroll
            for (int i = 0; i < 4; ++i) {
                const int idx = swz(wy * 64 + i * 16 + fr, fk);
                ah[i] = *(const short8*)&Ahs[idx];
                al[i] = *(const short8*)&Als[idx];
            }
#pragma unroll
            for (int j = 0; j < 4; ++j) {
                const int idx = swz(wx * 64 + j * 16 + fr, fk);
                bh8[j] = *(const short8*)&Bhs[idx];
                bl8[j] = *(const short8*)&Bls[idx];
            }
#pragma unroll
            for (int i = 0; i < 4; ++i)
#pragma unroll
                for (int j = 0; j < 4; ++j) {
                    acc[i][j] = __builtin_amdgcn_mfma_f32_16x16x32_bf16(ah[i], bh8[j], acc[i][j], 0, 0, 0);
                    acc[i][j] = __builtin_amdgcn_mfma_f32_16x16x32_bf16(al[i], bh8[j], acc[i][j], 0, 0, 0);
                    acc[i][j] = __builtin_amdgcn_mfma_f32_16x16x32_bf16(ah[i], bl8[j], acc[i][j], 0, 0, 0);
                }
        }
    }

    const int fr = lane & 15;
    const int fq = lane >> 4;
#pragma unroll
    for (int j = 0; j < 4; ++j) {
        const int n = n0 + wx * 64 + j * 16 + fr;
        const float bj = BIAS ? bias[n] : 0.0f;
#pragma unroll
        for (int i = 0; i < 4; ++i)
#pragma unroll
            for (int r = 0; r < 4; ++r) {
                const int m = m0 + wy * 64 + i * 16 + fq * 4 + r;
                const float val = acc[i][j][r] + bj;
                if (STORE == 0) {
                    Cf[(long)m * ldc + n] = val;
                } else if (STORE == 2) {
                    const int b = m >> 11, s = m & 2047, h = n >> 6, d = n & 63;
                    unsigned short hh, ll; split2(val, hh, ll);
                    const long idx = (((long)(b * N_HEADS + h)) * SS + s) * 64 + d;
                    Ch[idx] = hh; Cl[idx] = ll;
                } else {  // STORE 3
                    const int b = m >> 11, s = m & 2047, h = n >> 6, d = n & 63;
                    unsigned short hh, ll; split2(val, hh, ll);
                    const long idx = (((long)(b * N_HEADS + h)) * 64 + d) * SS + s;
                    Ch[idx] = hh; Cl[idx] = ll;
                }
            }
    }
}

// ---------------------------------------------------------------------------
// Fused scores + softmax + PV.  One block = 128 q-rows of one (b,h).
//   pass A: S = (Q K^T)/8 via MFMA, exact online (m,l) per row, raw S -> attn
//   reduce: combine (m,l) across the two wx-waves -> sm_m / sm_rl
//   pass B: read S back, p = exp(s-m)*rl -> attn (final) and split-bf16 LDS;
//           O += P V via MFMA.  O -> oh [b,s,h*64+d].
// grid: x = z (same-XCD grouping: 32 % 8 == 0), y = m-tile.
// ---------------------------------------------------------------------------
__global__ __launch_bounds__(256, 2) void attn_fused(
    const unsigned short* __restrict__ qh_hi, const unsigned short* __restrict__ qh_lo,
    const unsigned short* __restrict__ kh_hi, const unsigned short* __restrict__ kh_lo,
    const unsigned short* __restrict__ vt_hi, const unsigned short* __restrict__ vt_lo,
    float* __restrict__ attn, float* __restrict__ oh)
{
    const int z  = blockIdx.x;
    const int m0 = blockIdx.y * 128;
    const int b  = z >> 4;
    const int h  = z & 15;
    const int t  = threadIdx.x;
    const int lane = t & 63;
    const int wy = t >> 7;
    const int wx = (t >> 6) & 1;
    const int fr = lane & 15;
    const int fg = lane >> 4;

    __shared__ __align__(16) unsigned short Qh[128 * 64];   // pass A: Q planes; pass B: V planes
    __shared__ __align__(16) unsigned short Ql[128 * 64];
    __shared__ __align__(16) unsigned short Wh[128 * 64];   // pass A: K tile; pass B: P planes
    __shared__ __align__(16) unsigned short Wl[128 * 64];
    __shared__ float red_m[2][128];
    __shared__ float red_l[2][128];
    __shared__ float sm_m[128];
    __shared__ float sm_rl[128];

    const int sr = t >> 3;
    const int sc = (t & 7) * 8;

    float* attnZ = attn + (long)z * SS * SS;

    // ---- load Q planes once ----
#pragma unroll
    for (int p = 0; p < 4; ++p) {
        const long g = ((long)z * SS + m0 + sr + 32 * p) * 64 + sc;
        *(short8*)&Qh[swz(sr + 32 * p, sc)] = *(const short8*)&qh_hi[g];
        *(short8*)&Ql[swz(sr + 32 * p, sc)] = *(const short8*)&qh_lo[g];
    }

    float m_reg[16], l_reg[16];
#pragma unroll
    for (int e = 0; e < 16; ++e) { m_reg[e] = -3.0e38f; l_reg[e] = 0.f; }

    // ------------------------- pass A ------------------------------------
    for (int nt = 0; nt < 16; ++nt) {
        const int j0 = nt * 128;
        short8 kh8[4], kl8[4];
#pragma unroll
        for (int p = 0; p < 4; ++p) {
            const long g = ((long)z * SS + j0 + sr + 32 * p) * 64 + sc;
            kh8[p] = *(const short8*)&kh_hi[g];
            kl8[p] = *(const short8*)&kh_lo[g];
        }
        __syncthreads();
#pragma unroll
        for (int p = 0; p < 4; ++p) {
            const int idx = swz(sr + 32 * p, sc);
            *(short8*)&Wh[idx] = kh8[p];
            *(short8*)&Wl[idx] = kl8[p];
        }
        __syncthreads();

        f32x4 acc[4][4];
#pragma unroll
        for (int i = 0; i < 4; ++i)
#pragma unroll
            for (int j = 0; j < 4; ++j) acc[i][j] = (f32x4){0.f, 0.f, 0.f, 0.f};

#pragma unroll
        for (int ks = 0; ks < 2; ++ks) {
            const int fk = ks * 32 + fg * 8;
            short8 ah[4], al[4], bh8[4], bl8[4];
#pragma unroll
            for (int i = 0; i < 4; ++i) {
                const int idx = swz(wy * 64 + i * 16 + fr, fk);
                ah[i] = *(const short8*)&Qh[idx];
                al[i] = *(const short8*)&Ql[idx];
            }
#pragma unroll
            for (int j = 0; j < 4; ++j) {
                const int idx = swz(wx * 64 + j * 16 + fr, fk);
                bh8[j] = *(const short8*)&Wh[idx];
                bl8[j] = *(const short8*)&Wl[idx];
            }
#pragma unroll
            for (int i = 0; i < 4; ++i)
#pragma unroll
                for (int j = 0; j < 4; ++j) {
                    acc[i][j] = __builtin_amdgcn_mfma_f32_16x16x32_bf16(ah[i], bh8[j], acc[i][j], 0, 0, 0);
                    acc[i][j] = __builtin_amdgcn_mfma_f32_16x16x32_bf16(al[i], bh8[j], acc[i][j], 0, 0, 0);
                    acc[i][j] = __builtin_amdgcn_mfma_f32_16x16x32_bf16(ah[i], bl8[j], acc[i][j], 0, 0, 0);
                }
        }

#pragma unroll
        for (int i = 0; i < 4; ++i)
#pragma unroll
            for (int j = 0; j < 4; ++j) acc[i][j] *= 0.125f;

        // exact online (m,l) update over this tile's 4 cols per lane
#pragma unroll
        for (int i = 0; i < 4; ++i)
#pragma unroll
            for (int r = 0; r < 4; ++r) {
                const int e = i * 4 + r;
                const float tmax = fmaxf(fmaxf(acc[i][0][r], acc[i][1][r]),
                                         fmaxf(acc[i][2][r], acc[i][3][r]));
                const float mO = m_reg[e];
                const float mN = fmaxf(mO, tmax);
                const float s = __expf(acc[i][0][r] - mN) + __expf(acc[i][1][r] - mN)
                              + __expf(acc[i][2][r] - mN) + __expf(acc[i][3][r] - mN);
                l_reg[e] = l_reg[e] * __expf(mO - mN) + s;
                m_reg[e] = mN;
            }

        // store raw scaled S
#pragma unroll
        for (int i = 0; i < 4; ++i)
#pragma unroll
            for (int r = 0; r < 4; ++r) {
                const long row = (long)(m0 + wy * 64 + i * 16 + fg * 4 + r) * SS;
#pragma unroll
                for (int j = 0; j < 4; ++j)
                    attnZ[row + j0 + wx * 64 + j * 16 + fr] = acc[i][j][r];
            }
    }

    // ------------------- reduce (m,l): lanes, then wx ---------------------
#pragma unroll
    for (int e = 0; e < 16; ++e) {
        float mm = m_reg[e], ll = l_reg[e];
#pragma unroll
        for (int off = 1; off < 16; off <<= 1) {
            const float mo = __shfl_xor(mm, off);
            const float lo = __shfl_xor(ll, off);
            const float M = fmaxf(mm, mo);
            ll = ll * __expf(mm - M) + lo * __expf(mo - M);
            mm = M;
        }
        m_reg[e] = mm; l_reg[e] = ll;
    }
    if (fr == 0) {
#pragma unroll
        for (int e = 0; e < 16; ++e) {
            const int row = wy * 64 + (e >> 2) * 16 + fg * 4 + (e & 3);
            red_m[wx][row] = m_reg[e];
            red_l[wx][row] = l_reg[e];
        }
    }
    __syncthreads();
    if (t < 128) {
        const float ma = red_m[0][t], mb = red_m[1][t];
        const float M = fmaxf(ma, mb);
        const float L = red_l[0][t] * __expf(ma - M) + red_l[1][t] * __expf(mb - M);
        sm_m[t] = M;
        sm_rl[t] = 1.0f / L;
    }
    __syncthreads();

    // ------------------------- pass B ------------------------------------
    f32x4 oacc[4][2];
#pragma unroll
    for (int i = 0; i < 4; ++i)
#pragma unroll
        for (int j = 0; j < 2; ++j) oacc[i][j] = (f32x4){0.f, 0.f, 0.f, 0.f};

    for (int k0 = 0; k0 < SS; k0 += 64) {
        float4 a0[4], a1[4];
#pragma unroll
        for (int p = 0; p < 4; ++p) {
            const float* src = &attnZ[(long)(m0 + sr + 32 * p) * SS + k0 + sc];
            a0[p] = *(const float4*)src;
            a1[p] = *(const float4*)(src + 4);
        }
        short8 vh8[2], vl8[2];
#pragma unroll
        for (int p = 0; p < 2; ++p) {
            const long g = ((long)z * 64 + sr + 32 * p) * SS + k0 + sc;
            vh8[p] = *(const short8*)&vt_hi[g];
            vl8[p] = *(const short8*)&vt_lo[g];
        }
        __syncthreads();
#pragma unroll
        for (int p = 0; p < 4; ++p) {
            const int rl_ = sr + 32 * p;
            const float mR = sm_m[rl_], rR = sm_rl[rl_];
            float f[8] = {a0[p].x, a0[p].y, a0[p].z, a0[p].w,
                          a1[p].x, a1[p].y, a1[p].z, a1[p].w};
            union { short8 v; unsigned short u[8]; } ph, pl;
            float pv[8];
#pragma unroll
            for (int e = 0; e < 8; ++e) {
                pv[e] = __expf(f[e] - mR) * rR;
                split2(pv[e], ph.u[e], pl.u[e]);
            }
            float* dst = &attnZ[(long)(m0 + rl_) * SS + k0 + sc];
            *(float4*)dst = make_float4(pv[0], pv[1], pv[2], pv[3]);
            *(float4*)(dst + 4) = make_float4(pv[4], pv[5], pv[6], pv[7]);
            const int idx = swz(rl_, sc);
            *(short8*)&Wh[idx] = ph.v;
            *(short8*)&Wl[idx] = pl.v;
        }
#pragma unroll
        for (int p = 0; p < 2; ++p) {
            const int idx = swz(sr + 32 * p, sc);
            *(short8*)&Qh[idx] = vh8[p];
            *(short8*)&Ql[idx] = vl8[p];
        }
        __syncthreads();

#pragma unroll
        for (int ks = 0; ks < 2; ++ks) {
            const int fk = ks * 32 + fg * 8;
            short8 pa_h[4], pa_l[4], vb_h[2], vb_l[2];
#pragma unroll
            for (int i = 0; i < 4; ++i) {
                const int idx = swz(wy * 64 + i * 16 + fr, fk);
                pa_h[i] = *(const short8*)&Wh[idx];
                pa_l[i] = *(const short8*)&Wl[idx];
            }
#pragma unroll
            for (int jn = 0; jn < 2; ++jn) {
                const int idx = swz(wx * 32 + jn * 16 + fr, fk);
                vb_h[jn] = *(const short8*)&Qh[idx];
                vb_l[jn] = *(const short8*)&Ql[idx];
            }
#pragma unroll
            for (int i = 0; i < 4; ++i)
#pragma unroll
                for (int jn = 0; jn < 2; ++jn) {
                    oacc[i][jn] = __builtin_amdgcn_mfma_f32_16x16x32_bf16(pa_h[i], vb_h[jn], oacc[i][jn], 0, 0, 0);
                    oacc[i][jn] = __builtin_amdgcn_mfma_f32_16x16x32_bf16(pa_l[i], vb_h[jn], oacc[i][jn], 0, 0, 0);
                    oacc[i][jn] = __builtin_amdgcn_mfma_f32_16x16x32_bf16(pa_h[i], vb_l[jn], oacc[i][jn], 0, 0, 0);
                }
        }
    }

    // ---- O epilogue -> oh [b, s, h*64+d] ----
#pragma unroll
    for (int jn = 0; jn < 2; ++jn) {
        const int d = wx * 32 + jn * 16 + fr;
#pragma unroll
        for (int i = 0; i < 4; ++i)
#pragma unroll
            for (int r = 0; r < 4; ++r) {
                const int m = m0 + wy * 64 + i * 16 + fg * 4 + r;
                oh[((long)(b * SS + m)) * D_MODEL + h * 64 + d] = oacc[i][jn][r];
            }
    }
}

// ---------------------------------------------------------------------------
extern "C" void kernel_launch(void* const* d_in, const int* in_sizes, int n_in,
                              void* d_out, int out_size, void* d_ws, size_t ws_size,
                              hipStream_t stream)
{
    const float* q  = (const float*)d_in[0];
    const float* k  = (const float*)d_in[1];
    const float* v  = (const float*)d_in[2];
    const float* wq = (const float*)d_in[3];
    const float* bq = (const float*)d_in[4];
    const float* wk = (const float*)d_in[5];
    const float* bk = (const float*)d_in[6];
    const float* wv = (const float*)d_in[7];
    const float* bv = (const float*)d_in[8];
    const float* wo = (const float*)d_in[9];
    const float* bo = (const float*)d_in[10];

    float* out  = (float*)d_out;                         // [2,2048,1024]
    float* attn = out + (long)BB * SS * D_MODEL;         // [2,16,2048,2048]

    // --- workspace layout (64 MB) ---
    // [ 0, 8)MB qh_hi  [ 8,16)MB qh_lo    (dead after fused -> wo planes)
    // [16,24)MB kh_hi  [24,32)MB kh_lo
    // [32,40)MB vt_hi  [40,48)MB vt_lo    (vh transposed [b,h,d,s])
    // [48,64)MB oh fp32                   (holds wq/wk/wv planes until fused)
    char* ws = (char*)d_ws;
    unsigned short* qh_hi = (unsigned short*)ws;
    unsigned short* qh_lo = (unsigned short*)(ws + (8L  << 20));
    unsigned short* kh_hi = (unsigned short*)(ws + (16L << 20));
    unsigned short* kh_lo = (unsigned short*)(ws + (24L << 20));
    unsigned short* vt_hi = (unsigned short*)(ws + (32L << 20));
    unsigned short* vt_lo = (unsigned short*)(ws + (40L << 20));
    float*          oh    = (float*)(ws + (48L << 20));
    unsigned short* wq_hi = (unsigned short*)(ws + (48L << 20));
    unsigned short* wq_lo = (unsigned short*)(ws + (50L << 20));
    unsigned short* wk_hi = (unsigned short*)(ws + (52L << 20));
    unsigned short* wk_lo = (unsigned short*)(ws + (54L << 20));
    unsigned short* wv_hi = (unsigned short*)(ws + (56L << 20));
    unsigned short* wv_lo = (unsigned short*)(ws + (58L << 20));
    unsigned short* wo_hi = (unsigned short*)(ws);               // alias qh
    unsigned short* wo_lo = (unsigned short*)(ws + (2L << 20));  // alias qh

    const dim3 blk(256);
    const int NW4 = (D_MODEL * D_MODEL) / 4;

    hipLaunchKernelGGL(split_f32, dim3(1024), blk, 0, stream, wq, wq_hi, wq_lo, NW4);
    hipLaunchKernelGGL(split_f32, dim3(1024), blk, 0, stream, wk, wk_hi, wk_lo, NW4);
    hipLaunchKernelGGL(split_f32, dim3(1024), blk, 0, stream, wv, wv_hi, wv_lo, NW4);

    // Projections: M=4096, N=1024, K=1024 -> split planes (q,k) / split-T (v)
    const dim3 gproj(D_MODEL / 128, M_TOT / 128, 1);
    hipLaunchKernelGGL((gemm3<2, true>), gproj, blk, 0, stream,
                       q, D_MODEL, wq_hi, wq_lo, D_MODEL, bq,
                       (float*)nullptr, qh_hi, qh_lo, 0, D_MODEL);
    hipLaunchKernelGGL((gemm3<2, true>), gproj, blk, 0, stream,
                       k, D_MODEL, wk_hi, wk_lo, D_MODEL, bk,
                       (float*)nullptr, kh_hi, kh_lo, 0, D_MODEL);
    hipLaunchKernelGGL((gemm3<3, true>), gproj, blk, 0, stream,
                       v, D_MODEL, wv_hi, wv_lo, D_MODEL, bv,
                       (float*)nullptr, vt_hi, vt_lo, 0, D_MODEL);

    // Fused scores+softmax+PV: x = z (XCD-grouped), y = m-tile
    hipLaunchKernelGGL(attn_fused, dim3(BB * N_HEADS, SS / 128), blk, 0, stream,
                       qh_hi, qh_lo, kh_hi, kh_lo, vt_hi, vt_lo, attn, oh);

    // Split wo into the (now dead) qh region.
    hipLaunchKernelGGL(split_f32, dim3(1024), blk, 0, stream, wo, wo_hi, wo_lo, NW4);

    // Output projection: oh @ wo^T + bo -> out
    hipLaunchKernelGGL((gemm3<0, true>), gproj, blk, 0, stream,
                       oh, D_MODEL, wo_hi, wo_lo, D_MODEL, bo,
                       out, (unsigned short*)nullptr, (unsigned short*)nullptr,
                       D_MODEL, D_MODEL);
}